// Round 2
// baseline (634.756 us; speedup 1.0000x reference)
//
#include <hip/hip_runtime.h>
#include <stdint.h>

// IDUCell on MI355X (gfx950).
// Algebraic facts exploited:
//   x0e  == xtes[:, S-1, :]   (x0 = x[:, -1])
//   p0e  == ptes[:, S-1, :]
//   zt   is h-independent: zt = sigmoid(xtes@Wxtz + bxtz + x0z)  -> precomputed
// R7 == R6 resubmit (container infra failure, no measurement taken):
//   - recur poll rewritten: single 16-row batched tag load, unconditional
//     reload retry (issue-all-32 -> one waitcnt -> check-all). The old per-r8
//     exec-masked retry serialized 8 fabric round-trips (~5-7K cy/step).
//   - MFMA inner loop: 4 independent accumulation chains (even/odd kb) +
//     strength-reduced LDS addresses (2 per-lane bases + const offsets).
//   - fast transcendentals on the serial path: __expf + v_rcp_f32 sigmoid,
//     branch-free tanh = 1 - 2/(e^{2x}+1). Also in GEMM2's zt epilogue.
//   - publish stores issued before hts stores in recur epilogue.
//   - x0es broadcast moved out of GEMM1 epilogue (divergent 64-deep strided
//     store loop) into a dedicated coalesced float4 broadcast kernel.

using bf16 = __bf16;
typedef __attribute__((ext_vector_type(8))) __bf16 bf16x8;
typedef __attribute__((ext_vector_type(4))) float f32x4;

#define B_DIM 64
#define S_DIM 64
#define F_DIM 4096
#define H_DIM 1024
#define C_DIM 31

// ---------------- cast x -> bf16  +  tag h0 ----------------
__global__ void cast_tag_kernel(const float* __restrict__ x, bf16* __restrict__ xbf,
                                const float* __restrict__ h0, unsigned* __restrict__ hT0) {
  int bx = blockIdx.x;
  if (bx < 8192) {
    int i = bx * 256 + threadIdx.x;   // 8 elems per thread
    const float4* p = (const float4*)x + (size_t)i * 2;
    float4 a = p[0], b = p[1];
    bf16x8 v;
    v[0] = (bf16)a.x; v[1] = (bf16)a.y; v[2] = (bf16)a.z; v[3] = (bf16)a.w;
    v[4] = (bf16)b.x; v[5] = (bf16)b.y; v[6] = (bf16)b.z; v[7] = (bf16)b.w;
    ((bf16x8*)xbf)[i] = v;
  } else {
    int i = (bx - 8192) * 256 + threadIdx.x;  // 65536 total
    union { bf16 b; unsigned short u; } cv;
    cv.b = (bf16)h0[i];
    __hip_atomic_store(hT0 + i, ((unsigned)cv.u << 16), __ATOMIC_RELAXED,
                       __HIP_MEMORY_SCOPE_AGENT);
  }
}

// ---------------- all weight transposes, one launch ----------------
__device__ __forceinline__ void tr64(const float* __restrict__ in, bf16* __restrict__ out,
                                     int R, int C, int tR, int tC) {
  __shared__ float t[64][65];
  int tx = threadIdx.x & 63, ty = threadIdx.x >> 6;  // ty 0..3
#pragma unroll
  for (int i = 0; i < 16; ++i) {
    int r = tR + i * 4 + ty, c = tC + tx;
    t[i * 4 + ty][tx] = (r < R && c < C) ? in[(size_t)r * C + c] : 0.f;
  }
  __syncthreads();
#pragma unroll
  for (int i = 0; i < 16; ++i) {
    int c = tC + i * 4 + ty, r = tR + tx;
    if (c < C && r < R) out[(size_t)c * R + r] = (bf16)t[tx][i * 4 + ty];
  }
}

// flat grid 2576: [0,1024) Wxe (64x16 tiles); [1024,2560) six 1024^2; [2560,2576) Wep
__global__ void transpose_all(const float* __restrict__ Wxe, bf16* __restrict__ WxeT,
                              const float* __restrict__ a0, const float* __restrict__ a1,
                              const float* __restrict__ a2, const float* __restrict__ a3,
                              const float* __restrict__ a4, const float* __restrict__ a5,
                              bf16* __restrict__ o0, bf16* __restrict__ o1,
                              bf16* __restrict__ o2,
                              const float* __restrict__ Wep, bf16* __restrict__ WepT) {
  int id = blockIdx.x;
  if (id < 1024) {
    tr64(Wxe, WxeT, 4096, 1024, (id & 63) * 64, (id >> 6) * 64);
  } else if (id < 2560) {
    int q = id - 1024, z = q >> 8, t = q & 255;
    const float* in = z == 0 ? a0 : z == 1 ? a1 : z == 2 ? a2 : z == 3 ? a3 : z == 4 ? a4 : a5;
    bf16* out = (z < 2 ? o0 : z < 4 ? o1 : o2) + (size_t)(z & 1) * 1048576;
    tr64(in, out, 1024, 1024, (t & 15) * 64, (t >> 4) * 64);
  } else {
    tr64(Wep, WepT, 1024, 31, (id - 2560) * 64, 0);
  }
}

// ---------------- coalesced x0es broadcast ----------------
// x0es[b, sp, :] = xtes[b, 63, :] for all sp. 1024 blocks x 256 thr, float4.
__global__ void bcast_x0es(const float* __restrict__ xtesO, float* __restrict__ x0es) {
  int b = blockIdx.x >> 4, c = blockIdx.x & 15;  // 4 sp-rows per block
  float4 v = ((const float4*)(xtesO + ((size_t)b * 64 + 63) * 1024))[threadIdx.x];
  float4* dst = (float4*)(x0es + (size_t)b * 65536 + (size_t)c * 4096) + threadIdx.x;
#pragma unroll
  for (int i = 0; i < 4; ++i) dst[i * 256] = v;
}

// ---------------- MFMA GEMM  (A: MxK row-major bf16, B: B^T = NxK row-major bf16) ----------
// 128x128 tile, BK=64, 256 threads (4 waves, 2x2), 16x16x32 bf16 MFMA.
// global_load_lds width=16; XOR swizzle applied on the SOURCE address.
// MODE 2 uses gridDim.z K-split with atomicAdd epilogue (outA pre-zeroed).
template <int MODE>
__launch_bounds__(256, 2)
__global__ void gemm_bt(const bf16* __restrict__ A, const bf16* __restrict__ B,
                        int M, int N, int K, int lda,
                        const float* __restrict__ bias0,
                        const float* __restrict__ bias1,
                        const float* __restrict__ bias2,
                        const float* __restrict__ x0rz,
                        float* __restrict__ outA,
                        float* __restrict__ outB,
                        float* __restrict__ outC,
                        float* __restrict__ outD,
                        bf16* __restrict__ outBf) {
  __shared__ bf16 ldsA[128 * 64];
  __shared__ bf16 ldsB[128 * 64];
  const int tid = threadIdx.x;
  const int lane = tid & 63;
  const int wave = tid >> 6;
  const int quad = lane >> 4;
  const int l15 = lane & 15;
  const int wm = wave & 1, wn = wave >> 1;
  const int m0 = blockIdx.x * 128, n0 = blockIdx.y * 128;
  const int kPer = K / gridDim.z;
  const int k0 = blockIdx.z * kPer;

  f32x4 acc[4][4] = {};

  for (int kc = k0; kc < k0 + kPer; kc += 64) {
#pragma unroll
    for (int i = 0; i < 4; ++i) {
      int qb = i * 256 + wave * 64;   // wave's 16B-chunk base (uniform)
      int q = qb + lane;
      int r = q >> 3, cs = q & 7;
      int c = cs ^ (r & 7);           // swizzle on the source side
      int gr = m0 + r; if (gr > M - 1) gr = M - 1;  // clamp for M<128 tiles
      __builtin_amdgcn_global_load_lds(
          (const __attribute__((address_space(1))) unsigned int*)(A + (size_t)gr * lda + kc + c * 8),
          (__attribute__((address_space(3))) unsigned int*)(ldsA + (size_t)qb * 8),
          16, 0, 0);
      __builtin_amdgcn_global_load_lds(
          (const __attribute__((address_space(1))) unsigned int*)(B + (size_t)(n0 + r) * K + kc + c * 8),
          (__attribute__((address_space(3))) unsigned int*)(ldsB + (size_t)qb * 8),
          16, 0, 0);
    }
    __syncthreads();
#pragma unroll
    for (int ks = 0; ks < 2; ++ks) {
      bf16x8 af[4], bfr[4];
      int ch = ks * 4 + quad;
#pragma unroll
      for (int t = 0; t < 4; ++t) {
        int ar = wm * 64 + t * 16 + l15;
        af[t] = *(const bf16x8*)(ldsA + ar * 64 + ((ch ^ (ar & 7)) * 8));
        int br = wn * 64 + t * 16 + l15;
        bfr[t] = *(const bf16x8*)(ldsB + br * 64 + ((ch ^ (br & 7)) * 8));
      }
#pragma unroll
      for (int mt = 0; mt < 4; ++mt)
#pragma unroll
        for (int nt = 0; nt < 4; ++nt)
          acc[mt][nt] = __builtin_amdgcn_mfma_f32_16x16x32_bf16(
              af[mt], bfr[nt], acc[mt][nt], 0, 0, 0);
    }
    __syncthreads();
  }

#pragma unroll
  for (int mt = 0; mt < 4; ++mt) {
#pragma unroll
    for (int nt = 0; nt < 4; ++nt) {
#pragma unroll
      for (int i = 0; i < 4; ++i) {
        int m = m0 + wm * 64 + mt * 16 + quad * 4 + i;
        int n = n0 + wn * 64 + nt * 16 + l15;
        if (m >= M) continue;
        float v = acc[mt][nt][i];
        if (MODE == 0) {  // GEMM1: xtes = relu(.+bxe) -> f32 + bf16
          v += bias0[n];
          v = fmaxf(v, 0.f);
          outA[(size_t)m * 1024 + n] = v;
          outBf[(size_t)m * 1024 + n] = (bf16)v;
          // x0es broadcast handled by bcast_x0es (coalesced)
        } else if (MODE == 1) {  // GEMM2 fused: zt | xth1 | ptes (+p0es)
          if (n < 1024) {
            float z = v + bias0[n] + x0rz[(size_t)(m >> 6) * 2048 + 1024 + n];
            outA[(size_t)m * 1024 + n] =
                __builtin_amdgcn_rcpf(1.f + __expf(-z));  // zt (fast sigmoid)
          } else if (n < 2048) {
            outB[(size_t)m * 1024 + (n - 1024)] = v + bias1[n - 1024];  // xth1
          } else if (n < 2048 + C_DIM) {
            float pv = v + bias2[n - 2048];
            outC[(size_t)m * C_DIM + (n - 2048)] = pv;  // ptes
            if ((m & 63) == 63) {  // -> p0es[b, :, c]  (31 cols, cheap)
              size_t base = (size_t)(m >> 6) * 64 * C_DIM + (n - 2048);
              for (int sp = 0; sp < 64; ++sp) outD[base + (size_t)sp * C_DIM] = pv;
            }
          }
        } else {  // MODE 2: x0rz partial (K-split), atomic accumulate
          if (k0 == 0) v += (n < 1024 ? bias0[n] : bias1[n - 1024]);
          atomicAdd(outA + (size_t)m * 2048 + n, v);
        }
      }
    }
  }
}

// ---------------- recurrence (tagged, full-K per wave) ----------------
// 64 blocks: j = bx>>2 (strip of 64 cols), g = bx&3 (16 batch rows).
// Wave w owns cols [64j+16w, +16) with full-K weights in VGPRs/AGPRs.
// Per step: batched cooperative tagged load (32 loads in flight, one wait,
// check-all, unconditional-reload retry) -> LDS dbuf -> one __syncthreads ->
// 64 MFMA (4 independent chains) -> per-wave epilogue + tagged publish.
// Safety induction: publishing tag s+1 requires the whole block completed its
// cooperative read of tag s (barrier + full-K MFMA data dependence), so buffer
// (s+1)&1 is only overwritten after every same-domain block has finished
// reading tag s-1 from it. Tag values for step s are stable throughout this
// block's step-s poll (no block can publish s+2 before this block publishes
// s+1), so unconditional reloads of already-valid rows are safe.
#define TAG_OK(v, w) \
  ((((unsigned)(v) & 0xFFFFu) == (w)) & (((unsigned)((v) >> 32) & 0xFFFFu) == (w)))

__launch_bounds__(256, 1)
__global__ void recur_kernel(const bf16* __restrict__ WrecT,
                             const float* __restrict__ bhr,
                             const float* __restrict__ bh1h1,
                             const float* __restrict__ x0rz,
                             const float* __restrict__ ztAll,
                             const float* __restrict__ xth1All,
                             const float* __restrict__ h0,
                             unsigned* hT0,
                             unsigned* hT1,
                             float* __restrict__ hts) {
  __shared__ bf16 ldsA[2][16 * 1024];  // 2 x 32 KB staged h, 16B-chunk XOR swizzle
  const int tid = threadIdx.x;
  const int lane = tid & 63, wave = tid >> 6;
  const int quad = lane >> 4, l15 = lane & 15;
  const int j = blockIdx.x >> 2;   // strip (cols 64j..64j+64)
  const int g = blockIdx.x & 3;    // batch domain (rows 16g..16g+16)
  const int col = j * 64 + wave * 16 + l15;

  // full-K resident weights for this lane's column (2 matrices x 32 k-tiles)
  bf16x8 wr[32], wh[32];
#pragma unroll
  for (int kb = 0; kb < 32; ++kb) {
    wr[kb] = *(const bf16x8*)(WrecT + (size_t)col * 1024 + kb * 32 + quad * 8);
    wh[kb] = *(const bf16x8*)(WrecT + (size_t)(1024 + col) * 1024 + kb * 32 + quad * 8);
  }
  float hb_ = bh1h1[col];
  float rb[4], hloc[4];
#pragma unroll
  for (int i = 0; i < 4; ++i) {
    int b = g * 16 + quad * 4 + i;
    rb[i] = bhr[col] + x0rz[(size_t)b * 2048 + col];  // bhr + x0r
    hloc[i] = h0[(size_t)b * 1024 + col];             // fp32 carry
  }

  // strength-reduced LDS read bases for the MFMA loop:
  // addr(kb) = l15*2048 + (kb>>1)*128 + offP, P = kb&1
  const int off0 = ((quad ^ (l15 & 7)) * 16);
  const int off1 = (((4 + quad) ^ (l15 & 7)) * 16);

  for (int s = 0; s < 64; ++s) {
    const unsigned want = (unsigned)s;
    const unsigned long long* __restrict__ src =
        (const unsigned long long*)(((s & 1) ? hT1 : hT0) + (size_t)g * 16384) + tid * 2;

    // ---- batched tagged load: thread t <-> 16B vec t of each of 16 rows ----
    // issue all 32 loads first (critical path), then the gate-input prefetch.
    unsigned long long qa[16], qb[16];
#pragma unroll
    for (int r = 0; r < 16; ++r) {
      qa[r] = __hip_atomic_load(src + (size_t)r * 512, __ATOMIC_RELAXED,
                                __HIP_MEMORY_SCOPE_AGENT);
      qb[r] = __hip_atomic_load(src + (size_t)r * 512 + 1, __ATOMIC_RELAXED,
                                __HIP_MEMORY_SCOPE_AGENT);
    }
    float zt[4], xh[4];
#pragma unroll
    for (int i = 0; i < 4; ++i) {
      size_t mrow = ((size_t)(g * 16 + quad * 4 + i) * 64 + s) * 1024 + col;
      zt[i] = ztAll[mrow];
      xh[i] = xth1All[mrow];
    }
    // check-all / reload-all retry: one waitcnt per iteration, no per-vector
    // branches on the load side -> poll iteration ~= one fabric latency.
    for (int it = 0; ; ++it) {
      unsigned miss = 0;
#pragma unroll
      for (int r = 0; r < 16; ++r)
        if (!(TAG_OK(qa[r], want) & TAG_OK(qb[r], want))) miss |= 1u << r;
      if (!miss || it > (1 << 17)) break;
#pragma unroll
      for (int r = 0; r < 16; ++r) {
        qa[r] = __hip_atomic_load(src + (size_t)r * 512, __ATOMIC_RELAXED,
                                  __HIP_MEMORY_SCOPE_AGENT);
        qb[r] = __hip_atomic_load(src + (size_t)r * 512 + 1, __ATOMIC_RELAXED,
                                  __HIP_MEMORY_SCOPE_AGENT);
      }
    }
    // pack high halves -> bf16, write into swizzled chunk layout
    bf16* dstL = ldsA[s & 1];
#pragma unroll
    for (int r = 0; r < 16; ++r) {
      unsigned d0 = (unsigned)qa[r], d1 = (unsigned)(qa[r] >> 32);
      unsigned d2 = (unsigned)qb[r], d3 = (unsigned)(qb[r] >> 32);
      unsigned long long pk =
          ((unsigned long long)((d2 >> 16) | (d3 & 0xFFFF0000u)) << 32) |
          ((d0 >> 16) | (d1 & 0xFFFF0000u));
      int cc = ((tid >> 1) & 0x78) | (((tid >> 1) ^ r) & 7);
      *(unsigned long long*)((char*)dstL + r * 2048 + cc * 16 + (tid & 1) * 8) = pk;
    }
    __syncthreads();  // the single per-step barrier

    // full-K MFMA: A from LDS, weights from regs. 4 independent chains.
    f32x4 racc0 = {0.f, 0.f, 0.f, 0.f}, racc1 = {0.f, 0.f, 0.f, 0.f};
    f32x4 hacc0 = {0.f, 0.f, 0.f, 0.f}, hacc1 = {0.f, 0.f, 0.f, 0.f};
    const char* baseL = (const char*)dstL + l15 * 2048;
#pragma unroll
    for (int kb = 0; kb < 32; kb += 2) {
      bf16x8 af0 = *(const bf16x8*)(baseL + (kb >> 1) * 128 + off0);
      bf16x8 af1 = *(const bf16x8*)(baseL + (kb >> 1) * 128 + off1);
      racc0 = __builtin_amdgcn_mfma_f32_16x16x32_bf16(af0, wr[kb], racc0, 0, 0, 0);
      hacc0 = __builtin_amdgcn_mfma_f32_16x16x32_bf16(af0, wh[kb], hacc0, 0, 0, 0);
      racc1 = __builtin_amdgcn_mfma_f32_16x16x32_bf16(af1, wr[kb + 1], racc1, 0, 0, 0);
      hacc1 = __builtin_amdgcn_mfma_f32_16x16x32_bf16(af1, wh[kb + 1], hacc1, 0, 0, 0);
    }

    // per-wave epilogue: compute all 4 h_next (ILP across i), publish first.
    unsigned* dst = (s & 1) ? hT0 : hT1;
    float hn[4];
#pragma unroll
    for (int i = 0; i < 4; ++i) {
      float ra = racc0[i] + racc1[i];
      float ha = hacc0[i] + hacc1[i];
      float rt = __builtin_amdgcn_rcpf(1.f + __expf(-(ra + rb[i])));      // sigmoid
      float e2 = __expf(2.f * (xh[i] + rt * (ha + hb_)));
      float th = 1.f - 2.f * __builtin_amdgcn_rcpf(e2 + 1.f);             // tanh
      hn[i] = (1.f - zt[i]) * th + zt[i] * hloc[i];
      hloc[i] = hn[i];
    }
    if (s < 63) {
#pragma unroll
      for (int i = 0; i < 4; ++i) {
        int b = g * 16 + quad * 4 + i;
        union { bf16 b16; unsigned short u; } cv;
        cv.b16 = (bf16)hn[i];
        __hip_atomic_store(dst + (size_t)b * 1024 + col,
                           ((unsigned)cv.u << 16) | (unsigned)(s + 1),
                           __ATOMIC_RELAXED, __HIP_MEMORY_SCOPE_AGENT);
      }
    }
#pragma unroll
    for (int i = 0; i < 4; ++i) {
      size_t mrow = ((size_t)(g * 16 + quad * 4 + i) * 64 + s) * 1024 + col;
      hts[mrow] = hn[i];
    }
    // no trailing barrier: next step writes the other LDS buffer, and tag
    // dependencies prevent any wave from running >1 step ahead of its block.
  }
}

// ---------------- launch ----------------
extern "C" void kernel_launch(void* const* d_in, const int* in_sizes, int n_in,
                              void* d_out, int out_size, void* d_ws, size_t ws_size,
                              hipStream_t stream) {
  const float* x     = (const float*)d_in[0];
  const float* h0    = (const float*)d_in[1];
  const float* Wxe   = (const float*)d_in[2];
  const float* bxe   = (const float*)d_in[3];
  const float* Wep   = (const float*)d_in[4];
  const float* bep   = (const float*)d_in[5];
  const float* Whr   = (const float*)d_in[6];
  const float* bhr   = (const float*)d_in[7];
  const float* Wx0r  = (const float*)d_in[8];
  const float* bx0r  = (const float*)d_in[9];
  const float* Wxtz  = (const float*)d_in[10];
  const float* bxtz  = (const float*)d_in[11];
  const float* Wx0z  = (const float*)d_in[12];
  const float* bx0z  = (const float*)d_in[13];
  const float* Wxth1 = (const float*)d_in[14];
  const float* bxth1 = (const float*)d_in[15];
  const float* Wh1h1 = (const float*)d_in[16];
  const float* bh1h1 = (const float*)d_in[17];

  float* out   = (float*)d_out;
  float* hts   = out;                 // (64,64,1024)
  float* ptes  = out + 4194304;       // (64,64,31)
  float* p0es  = out + 4321280;       // (64,64,31)
  float* xtesO = out + 4448256;       // (64,64,1024)
  float* x0es  = out + 8642560;       // (64,64,1024)

  char* ws = (char*)d_ws;
  size_t off = 0;
  auto alloc = [&](size_t bytes) -> char* {
    char* p = ws + off;
    off += (bytes + 255) & ~(size_t)255;
    return p;
  };
  // x_bf zone is dead after GEMM1; reused for ztAll/xth1All (exact fit 32 MB)
  bf16*  xbf     = (bf16*)alloc(33554432);
  float* ztAll   = (float*)xbf;
  float* xth1All = (float*)((char*)xbf + 16777216);
  bf16*  WxeT    = (bf16*)alloc(8388608);            // 1024 x 4096
  bf16*  W2T     = (bf16*)alloc((size_t)2176 * 1024 * 2);  // [Wxtz^T;Wxth1^T;Wep^T pad]
  bf16*  WrecT   = (bf16*)alloc(4194304);            // [Whr^T;Wh1h1^T] 2048x1024
  bf16*  Wx0T    = (bf16*)alloc(4194304);            // [Wx0r^T;Wx0z^T]
  bf16*  xtesBf  = (bf16*)alloc(8388608);            // 4096 x 1024
  float* x0rz    = (float*)alloc(524288);            // 64 x 2048
  unsigned* hT0  = (unsigned*)alloc(262144);         // tagged h, even steps
  unsigned* hT1  = (unsigned*)alloc(262144);         // tagged h, odd steps

  hipMemsetAsync(W2T, 0, (size_t)2176 * 1024 * 2, stream);  // zero pad rows
  hipMemsetAsync(x0rz, 0, 524288, stream);                  // atomic K-split acc

  dim3 tb(256);
  cast_tag_kernel<<<8448, tb, 0, stream>>>(x, xbf, h0, hT0);
  transpose_all<<<2576, tb, 0, stream>>>(Wxe, WxeT,
                                         Whr, Wh1h1, Wxtz, Wxth1, Wx0r, Wx0z,
                                         WrecT, W2T, Wx0T,
                                         Wep, W2T + 2048 * 1024);

  // GEMM1: xtes (f32 + bf16)
  gemm_bt<0><<<dim3(32, 8), tb, 0, stream>>>(xbf, WxeT, 4096, 1024, 4096, 4096,
                                             bxe, nullptr, nullptr, nullptr,
                                             xtesO, nullptr, nullptr, nullptr, xtesBf);
  // coalesced x0es broadcast (reads xtes row 63 per batch)
  bcast_x0es<<<1024, tb, 0, stream>>>(xtesO, x0es);
  // x0rz = x0e@[Wx0r|Wx0z]+b, K-split 4 with atomic accumulate
  gemm_bt<2><<<dim3(1, 16, 4), tb, 0, stream>>>(xtesBf + 63 * 1024, Wx0T, 64, 2048, 1024, 65536,
                                                bx0r, bx0z, nullptr, nullptr,
                                                x0rz, nullptr, nullptr, nullptr, nullptr);
  // GEMM2 fused: zt | xth1 | ptes (+ fused p0es broadcast)
  gemm_bt<1><<<dim3(32, 17), tb, 0, stream>>>(xtesBf, W2T, 4096, 2176, 1024, 1024,
                                              bxtz, bxth1, bep, x0rz,
                                              ztAll, xth1All, ptes, p0es, nullptr);

  recur_kernel<<<64, tb, 0, stream>>>(WrecT, bhr, bh1h1, x0rz, ztAll, xth1All,
                                      h0, hT0, hT1, hts);
}